// Round 6
// baseline (187.407 us; speedup 1.0000x reference)
//
#include <hip/hip_runtime.h>
#include <hip/hip_fp16.h>
#include <cmath>

#define N_IMG 128
#define MAX_R 36
#define N_CAP 128
#define MAX_W 32
#define DIM   512
#define NEGV  -1e30f

typedef unsigned short u16;
typedef unsigned int   u32;
typedef __attribute__((ext_vector_type(8))) short short8;
typedef __attribute__((ext_vector_type(4))) float f32x4;

#define NI_ELEMS (N_IMG * MAX_R * DIM)   // 2359296
#define NC_ELEMS (N_CAP * MAX_W * DIM)   // 2097152

// chunk geometry
#define A_CHUNK_BYTES 16384   // per (cg,kb): [hi 128x32][lo 128x32] bf16
#define B_CHUNK_BYTES 18432   // per (g,kb):  [hi 144x32][lo 144x32] bf16
#define BUF_BYTES     34816   // A + B
#define LDS_BYTES     (3 * 34816 + 10368)   // 3 buffers + sG16 = 114816

__device__ __forceinline__ u16 f2bf(float x) {
    u32 u = __float_as_uint(x);
    u32 r = u + 0x7fffu + ((u >> 16) & 1u);
    return (u16)(r >> 16);
}
__device__ __forceinline__ float bf2f(u16 h) {
    return __uint_as_float(((u32)h) << 16);
}
__device__ __forceinline__ void gload_lds16(const void* g, void* l) {
    __builtin_amdgcn_global_load_lds(
        (const __attribute__((address_space(1))) void*)g,
        (__attribute__((address_space(3))) void*)l, 16, 0, 0);
}

// ---------------------------------------------------------------------------
// Kernel 0: fp32 -> (hi,lo) bf16 split, pre-tiled + pre-swizzled.
// caps: chunk per (cg = c>>2, kb): row = (c&3)*32 + w  (128 rows x 32 k)
// imgs: chunk per (g = imgRow/144, kb): rowT = imgRow % 144 (packed, no pad)
// ---------------------------------------------------------------------------
__global__ __launch_bounds__(256) void convert_kernel(const float* __restrict__ imgs,
                                                      const float* __restrict__ caps,
                                                      u16* __restrict__ imgsT,
                                                      u16* __restrict__ capsT) {
    const size_t ni4 = NI_ELEMS / 4;
    const size_t total4 = (NI_ELEMS + NC_ELEMS) / 4;
    const size_t stride = (size_t)gridDim.x * blockDim.x;
    for (size_t p = (size_t)blockIdx.x * blockDim.x + threadIdx.x; p < total4; p += stride) {
        const bool isImg = p < ni4;
        const float4 v = isImg ? ((const float4*)imgs)[p] : ((const float4*)caps)[p - ni4];
        u16 h0 = f2bf(v.x), h1 = f2bf(v.y), h2 = f2bf(v.z), h3 = f2bf(v.w);
        u16 l0 = f2bf(v.x - bf2f(h0)), l1 = f2bf(v.y - bf2f(h1));
        u16 l2 = f2bf(v.z - bf2f(h2)), l3 = f2bf(v.w - bf2f(h3));
        uint2 hv, lv;
        hv.x = (u32)h0 | ((u32)h1 << 16);  hv.y = (u32)h2 | ((u32)h3 << 16);
        lv.x = (u32)l0 | ((u32)l1 << 16);  lv.y = (u32)l2 | ((u32)l3 << 16);
        if (isImg) {
            const int e = (int)(p * 4);
            const int imgRow = e >> 9, k = e & 511;
            const int g = imgRow / 144;
            const int rowT = imgRow - g * 144;
            const int kb = k >> 5;
            const int blk = ((k >> 3) & 3) ^ ((rowT >> 1) & 3);
            const size_t off = ((size_t)g * 16 + kb) * 9216 + rowT * 32 + blk * 8 + (k & 7);
            *(uint2*)(imgsT + off) = hv;
            *(uint2*)(imgsT + off + 4608) = lv;
        } else {
            const int e = (int)((p - ni4) * 4);
            const int R = e >> 9, k = e & 511;
            const int cg = R >> 7, row = R & 127;
            const int kb = k >> 5;
            const int blk = ((k >> 3) & 3) ^ ((row >> 1) & 3);
            const size_t off = ((size_t)cg * 16 + kb) * 8192 + row * 32 + blk * 8 + (k & 7);
            *(uint2*)(capsT + off) = hv;
            *(uint2*)(capsT + off + 4096) = lv;
        }
    }
}

// ---------------------------------------------------------------------------
// Kernel A: per-image Gram matrices, stored fp16: G16[i][a*36+b]
// ---------------------------------------------------------------------------
__global__ __launch_bounds__(256) void gram_kernel(const float* __restrict__ imgs,
                                                   __half* __restrict__ G16) {
    const int i = blockIdx.x;
    const int t = threadIdx.x;
    __shared__ float sImg[MAX_R][132];
    const float* base = imgs + (size_t)i * MAX_R * DIM;

    const int ap = t / 12;
    const int bt = t % 12;
    const bool active = ap < 18;
    float acc[2][3] = {};

    for (int ch = 0; ch < 4; ++ch) {
        for (int idx = t; idx < MAX_R * 32; idx += 256) {
            const int row = idx >> 5, col = idx & 31;
            *(float4*)&sImg[row][col * 4] =
                *(const float4*)(base + row * DIM + ch * 128 + col * 4);
        }
        __syncthreads();
        if (active) {
            #pragma unroll
            for (int k4 = 0; k4 < 32; ++k4) {
                float4 a0 = *(float4*)&sImg[ap * 2 + 0][k4 * 4];
                float4 a1 = *(float4*)&sImg[ap * 2 + 1][k4 * 4];
                float4 b0 = *(float4*)&sImg[bt * 3 + 0][k4 * 4];
                float4 b1 = *(float4*)&sImg[bt * 3 + 1][k4 * 4];
                float4 b2 = *(float4*)&sImg[bt * 3 + 2][k4 * 4];
                acc[0][0] += a0.x*b0.x + a0.y*b0.y + a0.z*b0.z + a0.w*b0.w;
                acc[0][1] += a0.x*b1.x + a0.y*b1.y + a0.z*b1.z + a0.w*b1.w;
                acc[0][2] += a0.x*b2.x + a0.y*b2.y + a0.z*b2.z + a0.w*b2.w;
                acc[1][0] += a1.x*b0.x + a1.y*b0.y + a1.z*b0.z + a1.w*b0.w;
                acc[1][1] += a1.x*b1.x + a1.y*b1.y + a1.z*b1.z + a1.w*b1.w;
                acc[1][2] += a1.x*b2.x + a1.y*b2.y + a1.z*b2.z + a1.w*b2.w;
            }
        }
        __syncthreads();
    }
    if (active) {
        __half* g = G16 + (size_t)i * (MAX_R * MAX_R);
        #pragma unroll
        for (int x = 0; x < 2; ++x)
            #pragma unroll
            for (int y = 0; y < 3; ++y)
                g[(ap * 2 + x) * MAX_R + (bt * 3 + y)] = __float2half(acc[x][y]);
    }
}

// ---------------------------------------------------------------------------
// Kernel B: block = 4 caps (128 rows) x 4 images (144 packed cols).
// 6 waves (2m x 3n), wave tile 64x48, 16x16x32 bf16 MFMA, 3-pass hi/lo.
// 3-deep staging pipeline: counted vmcnt (never 0 in main loop) + raw
// s_barrier — no per-step full drain (the R5 stall). 1 block/CU.
// ---------------------------------------------------------------------------
__global__ __launch_bounds__(384, 1) void vsc_mfma_kernel(const u16* __restrict__ imgsT,
                                const u16* __restrict__ capsT,
                                const int* __restrict__ img_lens,
                                const int* __restrict__ cap_lens,
                                const __half* __restrict__ G16,
                                float* __restrict__ out) {
    extern __shared__ __align__(16) char smem[];
    const int bid = blockIdx.x;
    const int cg = bid & 31;      // cap group (4 caps = 128 rows)
    const int g  = bid >> 5;      // image tile (4 imgs = 144 cols)
    const int t = threadIdx.x;
    const int wid = t >> 6;       // 0..5
    const int lane = t & 63;
    const int l15 = lane & 15;
    const int kblk = lane >> 4;
    const int wm = (wid < 3) ? 0 : 1;
    const int wn = wid - wm * 3;

    float* sS = (float*)smem;                       // overlay after K-loop
    __half* sG = (__half*)(smem + 3 * BUF_BYTES);

    // prologue: Gram (4 images, fp16) into LDS, then drain its vmcnt so the
    // counted staging pipeline starts from 0 outstanding.
    {
        const uint4* src = (const uint4*)(G16 + (size_t)g * 4 * 1296);
        uint4* dstv = (uint4*)sG;
        for (int idx = t; idx < 648; idx += 384)
            dstv[idx] = src[idx];
    }
    asm volatile("s_waitcnt vmcnt(0)" ::: "memory");
    __builtin_amdgcn_sched_barrier(0);

    const char* gA = (const char*)(capsT + (size_t)cg * 16 * 8192);
    const char* gB = (const char*)(imgsT + (size_t)g  * 16 * 9216);

    // stage one k-step: A 16KB (waves 0-3, 4 instr each), B 18KB (waves 4-5, 9 each)
    auto stage = [&](int kb, char* b) {
        if (wid < 4) {
            const char* src = gA + (size_t)kb * A_CHUNK_BYTES + wid * 4096 + lane * 16;
            char* dst = b + wid * 4096;
            #pragma unroll
            for (int j = 0; j < 4; ++j)
                gload_lds16(src + j * 1024, dst + j * 1024);
        } else {
            const int wb = wid - 4;
            const char* src = gB + (size_t)kb * B_CHUNK_BYTES + wb * 9216 + lane * 16;
            char* dst = b + 16384 + wb * 9216;
            #pragma unroll
            for (int j = 0; j < 9; ++j)
                gload_lds16(src + j * 1024, dst + j * 1024);
        }
    };

    f32x4 acc[4][3];
    #pragma unroll
    for (int mt = 0; mt < 4; ++mt)
        #pragma unroll
        for (int nt = 0; nt < 3; ++nt)
            acc[mt][nt] = (f32x4){0.f, 0.f, 0.f, 0.f};

    stage(0, smem);
    stage(1, smem + BUF_BYTES);
    stage(2, smem + 2 * BUF_BYTES);

    for (int kb = 0; kb < 16; ++kb) {
        // wait until stage(kb) landed: <= pend*N_w outstanding (per-wave count)
        const int pend = (kb < 14) ? 2 : ((kb == 14) ? 1 : 0);
        if (wid < 4) {
            if (pend == 2)      asm volatile("s_waitcnt vmcnt(8)"  ::: "memory");
            else if (pend == 1) asm volatile("s_waitcnt vmcnt(4)"  ::: "memory");
            else                asm volatile("s_waitcnt vmcnt(0)"  ::: "memory");
        } else {
            if (pend == 2)      asm volatile("s_waitcnt vmcnt(18)" ::: "memory");
            else if (pend == 1) asm volatile("s_waitcnt vmcnt(9)"  ::: "memory");
            else                asm volatile("s_waitcnt vmcnt(0)"  ::: "memory");
        }
        __builtin_amdgcn_sched_barrier(0);
        __builtin_amdgcn_s_barrier();
        __builtin_amdgcn_sched_barrier(0);

        char* cur = smem + (size_t)(kb % 3) * BUF_BYTES;

        short8 ah[4], al[4], bh[3], bl[3];
        #pragma unroll
        for (int mt = 0; mt < 4; ++mt) {
            const int row = wm * 64 + mt * 16 + l15;
            const int blk = kblk ^ ((row >> 1) & 3);
            ah[mt] = *(const short8*)(cur + row * 64 + blk * 16);
            al[mt] = *(const short8*)(cur + 8192 + row * 64 + blk * 16);
        }
        #pragma unroll
        for (int nt = 0; nt < 3; ++nt) {
            const int r = wn * 48 + nt * 16 + l15;
            const int blk = kblk ^ ((r >> 1) & 3);
            bh[nt] = *(const short8*)(cur + 16384 + r * 64 + blk * 16);
            bl[nt] = *(const short8*)(cur + 16384 + 9216 + r * 64 + blk * 16);
        }
        // own frag reads done, then block-wide: buffer kb%3 free for reuse
        asm volatile("s_waitcnt lgkmcnt(0)" ::: "memory");
        __builtin_amdgcn_sched_barrier(0);
        __builtin_amdgcn_s_barrier();
        __builtin_amdgcn_sched_barrier(0);

        if (kb < 13) stage(kb + 3, cur);

        #pragma unroll
        for (int mt = 0; mt < 4; ++mt)
            #pragma unroll
            for (int nt = 0; nt < 3; ++nt)
                acc[mt][nt] = __builtin_amdgcn_mfma_f32_16x16x32_bf16(ah[mt], bh[nt], acc[mt][nt], 0, 0, 0);
        #pragma unroll
        for (int mt = 0; mt < 4; ++mt)
            #pragma unroll
            for (int nt = 0; nt < 3; ++nt)
                acc[mt][nt] = __builtin_amdgcn_mfma_f32_16x16x32_bf16(ah[mt], bl[nt], acc[mt][nt], 0, 0, 0);
        #pragma unroll
        for (int mt = 0; mt < 4; ++mt)
            #pragma unroll
            for (int nt = 0; nt < 3; ++nt)
                acc[mt][nt] = __builtin_amdgcn_mfma_f32_16x16x32_bf16(al[mt], bh[nt], acc[mt][nt], 0, 0, 0);
    }

    __syncthreads();   // safe: no outstanding gload_lds (kb=15 waited vmcnt 0)

    // ---- sims -> LDS overlay (already / TEMPERATURE); col-XOR bank swizzle
    #pragma unroll
    for (int mt = 0; mt < 4; ++mt)
        #pragma unroll
        for (int nt = 0; nt < 3; ++nt) {
            const int col = wn * 48 + nt * 16 + l15;
            #pragma unroll
            for (int reg = 0; reg < 4; ++reg) {
                const int row = wm * 64 + mt * 16 + (lane >> 4) * 4 + reg;
                sS[row * 144 + (col ^ ((row >> 1) & 15))] = acc[mt][nt][reg] * 10.f;
            }
        }
    __syncthreads();

    // ---- postprocess: 512 tasks = 128 (cap,w) rows x 4 images
    for (int task = t; task < 512; task += 384) {
        const int pair = task & 127;
        const int j = task >> 7;
        const int q = pair >> 5, w = pair & 31;
        const int c = cg * 4 + q;
        const int i = g * 4 + j;
        float result = -1.0f;
        if (w < cap_lens[c]) {
            const int ilen = img_lens[i];   // >= 6 by construction
            const float* rowp = sS + pair * 144;
            const int xv = (pair >> 1) & 15;
            const int cb = j * 36;
            float t0 = NEGV, t1 = NEGV, t2 = NEGV, t3 = NEGV, t4 = NEGV;
            for (int r = 0; r < ilen; ++r) {
                const float v = rowp[(cb + r) ^ xv];
                if (v > t4) {
                    if (v > t0)      { t4=t3; t3=t2; t2=t1; t1=t0; t0=v; }
                    else if (v > t1) { t4=t3; t3=t2; t2=t1; t1=v; }
                    else if (v > t2) { t4=t3; t3=t2; t2=v; }
                    else if (v > t3) { t4=t3; t3=v; }
                    else             { t4=v; }
                }
            }
            const float kth = t4, m = t0;
            int   idxs[8];
            float pv[8];
            int cnt = 0;
            float sum = 0.f;
            for (int r = 0; r < ilen; ++r) {
                const float v = rowp[(cb + r) ^ xv];
                if (v >= kth) {
                    const float e = expf(v - m);
                    sum += e;
                    if (cnt < 8) { idxs[cnt] = r; pv[cnt] = e; ++cnt; }
                }
            }
            const float inv = 1.0f / sum;
            const __half* gj = sG + j * 1296;
            float num = 0.f, den2 = 0.f;
            for (int a = 0; a < cnt; ++a) {
                const float pa = pv[a] * inv;
                num += pa * rowp[(cb + idxs[a]) ^ xv];
                for (int b = 0; b < cnt; ++b)
                    den2 += pa * (pv[b] * inv) * __half2float(gj[idxs[a] * 36 + idxs[b]]);
            }
            num *= 0.1f;
            const float den = sqrtf(den2) + (-1e-8f);
            result = num / den;
        }
        out[((size_t)i * N_CAP + c) * MAX_W + w] = result;
    }
}

extern "C" void kernel_launch(void* const* d_in, const int* in_sizes, int n_in,
                              void* d_out, int out_size, void* d_ws, size_t ws_size,
                              hipStream_t stream) {
    const float* imgs     = (const float*)d_in[0];
    const float* caps     = (const float*)d_in[1];
    const int*   img_lens = (const int*)d_in[2];
    const int*   cap_lens = (const int*)d_in[3];
    float* out = (float*)d_out;

    // d_ws layout
    __half* G16 = (__half*)d_ws;                               // 331776 B
    u16* imgsT = (u16*)((char*)d_ws + 331776);                 // 32*16*9216 u16 = 9437184 B
    u16* capsT = imgsT + (size_t)32 * 16 * 9216;               // 32*16*8192 u16 = 8388608 B

    hipFuncSetAttribute((const void*)vsc_mfma_kernel,
                        hipFuncAttributeMaxDynamicSharedMemorySize, LDS_BYTES);

    convert_kernel<<<2048, 256, 0, stream>>>(imgs, caps, imgsT, capsT);
    gram_kernel<<<N_IMG, 256, 0, stream>>>(imgs, G16);
    vsc_mfma_kernel<<<1024, 384, LDS_BYTES, stream>>>(imgsT, capsT, img_lens, cap_lens, G16, out);
}

// Round 7
// 150.153 us; speedup vs baseline: 1.2481x; 1.2481x over previous
//
#include <hip/hip_runtime.h>
#include <hip/hip_fp16.h>
#include <cmath>

#define N_IMG 128
#define MAX_R 36
#define N_CAP 128
#define MAX_W 32
#define DIM   512
#define NEGV  -1e30f

typedef unsigned short u16;
typedef unsigned int   u32;
typedef __attribute__((ext_vector_type(8))) short short8;
typedef __attribute__((ext_vector_type(4))) float f32x4;

#define NI_ELEMS (N_IMG * MAX_R * DIM)   // 2359296
#define NC_ELEMS (N_CAP * MAX_W * DIM)   // 2097152

// chunk geometry (u16 counts)
#define A_CHUNK_U16 16384   // per (cg8,kb): [hi 256x32][lo 256x32]
#define B_CHUNK_U16 9216    // per (g,kb):   [hi 144x32][lo 144x32]
#define STAGE_BYTES 51200   // 32768 (A) + 18432 (B)
#define LDS_BYTES   (147456 + 10368)       // sS + sG16 = 157824 <= 160K

__device__ __forceinline__ u16 f2bf(float x) {
    u32 u = __float_as_uint(x);
    u32 r = u + 0x7fffu + ((u >> 16) & 1u);
    return (u16)(r >> 16);
}
__device__ __forceinline__ float bf2f(u16 h) {
    return __uint_as_float(((u32)h) << 16);
}
__device__ __forceinline__ void gload_lds16(const void* g, void* l) {
    __builtin_amdgcn_global_load_lds(
        (const __attribute__((address_space(1))) void*)g,
        (__attribute__((address_space(3))) void*)l, 16, 0, 0);
}

// ---------------------------------------------------------------------------
// Kernel 0: fp32 -> (hi,lo) bf16 split, pre-tiled + pre-swizzled.
// ---------------------------------------------------------------------------
__global__ __launch_bounds__(256) void convert_kernel(const float* __restrict__ imgs,
                                                      const float* __restrict__ caps,
                                                      u16* __restrict__ imgsT,
                                                      u16* __restrict__ capsT) {
    const size_t ni4 = NI_ELEMS / 4;
    const size_t total4 = (NI_ELEMS + NC_ELEMS) / 4;
    const size_t stride = (size_t)gridDim.x * blockDim.x;
    for (size_t p = (size_t)blockIdx.x * blockDim.x + threadIdx.x; p < total4; p += stride) {
        const bool isImg = p < ni4;
        const float4 v = isImg ? ((const float4*)imgs)[p] : ((const float4*)caps)[p - ni4];
        u16 h0 = f2bf(v.x), h1 = f2bf(v.y), h2 = f2bf(v.z), h3 = f2bf(v.w);
        u16 l0 = f2bf(v.x - bf2f(h0)), l1 = f2bf(v.y - bf2f(h1));
        u16 l2 = f2bf(v.z - bf2f(h2)), l3 = f2bf(v.w - bf2f(h3));
        uint2 hv, lv;
        hv.x = (u32)h0 | ((u32)h1 << 16);  hv.y = (u32)h2 | ((u32)h3 << 16);
        lv.x = (u32)l0 | ((u32)l1 << 16);  lv.y = (u32)l2 | ((u32)l3 << 16);
        if (isImg) {
            const int e = (int)(p * 4);
            const int imgRow = e >> 9, k = e & 511;
            const int g = imgRow / 144;
            const int rowT = imgRow - g * 144;
            const int kb = k >> 5;
            const int blk = ((k >> 3) & 3) ^ ((rowT >> 1) & 3);
            const size_t off = ((size_t)g * 16 + kb) * B_CHUNK_U16 + rowT * 32 + blk * 8 + (k & 7);
            *(uint2*)(imgsT + off) = hv;
            *(uint2*)(imgsT + off + 4608) = lv;
        } else {
            const int e = (int)((p - ni4) * 4);
            const int R = e >> 9, k = e & 511;
            const int cg8 = R >> 8, row = R & 255;
            const int kb = k >> 5;
            const int blk = ((k >> 3) & 3) ^ ((row >> 1) & 3);
            const size_t off = ((size_t)cg8 * 16 + kb) * A_CHUNK_U16 + row * 32 + blk * 8 + (k & 7);
            *(uint2*)(capsT + off) = hv;
            *(uint2*)(capsT + off + 8192) = lv;
        }
    }
}

// ---------------------------------------------------------------------------
// Kernel A: per-image Gram matrices, stored fp16: G16[i][a*36+b]
// ---------------------------------------------------------------------------
__global__ __launch_bounds__(256) void gram_kernel(const float* __restrict__ imgs,
                                                   __half* __restrict__ G16) {
    const int i = blockIdx.x;
    const int t = threadIdx.x;
    __shared__ float sImg[MAX_R][132];
    const float* base = imgs + (size_t)i * MAX_R * DIM;

    const int ap = t / 12;
    const int bt = t % 12;
    const bool active = ap < 18;
    float acc[2][3] = {};

    for (int ch = 0; ch < 4; ++ch) {
        for (int idx = t; idx < MAX_R * 32; idx += 256) {
            const int row = idx >> 5, col = idx & 31;
            *(float4*)&sImg[row][col * 4] =
                *(const float4*)(base + row * DIM + ch * 128 + col * 4);
        }
        __syncthreads();
        if (active) {
            #pragma unroll
            for (int k4 = 0; k4 < 32; ++k4) {
                float4 a0 = *(float4*)&sImg[ap * 2 + 0][k4 * 4];
                float4 a1 = *(float4*)&sImg[ap * 2 + 1][k4 * 4];
                float4 b0 = *(float4*)&sImg[bt * 3 + 0][k4 * 4];
                float4 b1 = *(float4*)&sImg[bt * 3 + 1][k4 * 4];
                float4 b2 = *(float4*)&sImg[bt * 3 + 2][k4 * 4];
                acc[0][0] += a0.x*b0.x + a0.y*b0.y + a0.z*b0.z + a0.w*b0.w;
                acc[0][1] += a0.x*b1.x + a0.y*b1.y + a0.z*b1.z + a0.w*b1.w;
                acc[0][2] += a0.x*b2.x + a0.y*b2.y + a0.z*b2.z + a0.w*b2.w;
                acc[1][0] += a1.x*b0.x + a1.y*b0.y + a1.z*b0.z + a1.w*b0.w;
                acc[1][1] += a1.x*b1.x + a1.y*b1.y + a1.z*b1.z + a1.w*b1.w;
                acc[1][2] += a1.x*b2.x + a1.y*b2.y + a1.z*b2.z + a1.w*b2.w;
            }
        }
        __syncthreads();
    }
    if (active) {
        __half* g = G16 + (size_t)i * (MAX_R * MAX_R);
        #pragma unroll
        for (int x = 0; x < 2; ++x)
            #pragma unroll
            for (int y = 0; y < 3; ++y)
                g[(ap * 2 + x) * MAX_R + (bt * 3 + y)] = __float2half(acc[x][y]);
    }
}

// ---------------------------------------------------------------------------
// Kernel B: block = 8 caps (256 rows) x 4 images (144 packed cols).
// 6 waves (2m x 3n), wave tile 128x48, 16x16x32 bf16 MFMA, 3-pass hi/lo.
// XCD-keyed bid remap: XCD = g & 7 (dispatch round-robins bid%8 over XCDs),
// so all 16 cap-blocks of an image-tile share one XCD's L2 -> B-panel
// (<=1.2 MB/XCD) becomes L2-resident instead of L3-streamed (R6 finding:
// kernel is global->LDS ingest-bound at ~3 TB/s, mostly L2 misses).
// ---------------------------------------------------------------------------
__global__ __launch_bounds__(384, 1) void vsc_mfma_kernel(const u16* __restrict__ imgsT,
                                const u16* __restrict__ capsT,
                                const int* __restrict__ img_lens,
                                const int* __restrict__ cap_lens,
                                const __half* __restrict__ G16,
                                float* __restrict__ out) {
    extern __shared__ __align__(16) char smem[];
    const int bid = blockIdx.x;
    const int x   = bid & 7;            // XCD key
    const int q   = bid >> 3;           // 0..63
    const int g   = (q >> 4) * 8 + x;   // image tile 0..31 (4 imgs each)
    const int cg8 = q & 15;             // cap group 0..15 (8 caps each)
    const int t = threadIdx.x;
    const int wid = t >> 6;       // 0..5
    const int lane = t & 63;
    const int l15 = lane & 15;
    const int kblk = lane >> 4;
    const int wm = (wid < 3) ? 0 : 1;
    const int wn = wid - wm * 3;

    float* sS = (float*)smem;
    __half* sG = (__half*)(smem + 147456);

    // prologue: Gram (4 images, fp16) into LDS
    {
        const uint4* src = (const uint4*)(G16 + (size_t)g * 4 * 1296);
        for (int idx = t; idx < 648; idx += 384)
            ((uint4*)sG)[idx] = src[idx];
    }

    const char* gA = (const char*)(capsT + (size_t)cg8 * 16 * A_CHUNK_U16);
    const char* gB = (const char*)(imgsT + (size_t)g  * 16 * B_CHUNK_U16);

    auto stage = [&](int kb, char* buf) {
        if (wid < 4) {          // A: 32768 B, 4 waves x 8 KB
            const char* src = gA + (size_t)kb * 32768 + wid * 8192 + lane * 16;
            char* dst = buf + wid * 8192;
            #pragma unroll
            for (int j = 0; j < 8; ++j)
                gload_lds16(src + j * 1024, dst + j * 1024);
        } else {                // B: 18432 B, 2 waves x 9 KB
            const int wb = wid - 4;
            const char* src = gB + (size_t)kb * 18432 + wb * 9216 + lane * 16;
            char* dst = buf + 32768 + wb * 9216;
            #pragma unroll
            for (int j = 0; j < 9; ++j)
                gload_lds16(src + j * 1024, dst + j * 1024);
        }
    };

    f32x4 acc[8][3];
    #pragma unroll
    for (int mt = 0; mt < 8; ++mt)
        #pragma unroll
        for (int nt = 0; nt < 3; ++nt)
            acc[mt][nt] = (f32x4){0.f, 0.f, 0.f, 0.f};

    stage(0, smem);
    __syncthreads();

    for (int kb = 0; kb < 16; ++kb) {
        char* cur = smem + (size_t)(kb & 1) * STAGE_BYTES;
        if (kb < 15) stage(kb + 1, smem + (size_t)((kb + 1) & 1) * STAGE_BYTES);

        short8 bh[3], bl[3], ah[8], al[8];
        #pragma unroll
        for (int nt = 0; nt < 3; ++nt) {
            const int r = wn * 48 + nt * 16 + l15;
            const int blk = kblk ^ ((r >> 1) & 3);
            bh[nt] = *(const short8*)(cur + 32768 + r * 64 + blk * 16);
            bl[nt] = *(const short8*)(cur + 32768 + 9216 + r * 64 + blk * 16);
        }
        #pragma unroll
        for (int mt = 0; mt < 8; ++mt) {
            const int row = wm * 128 + mt * 16 + l15;
            const int blk = kblk ^ ((row >> 1) & 3);
            ah[mt] = *(const short8*)(cur + row * 64 + blk * 16);
            al[mt] = *(const short8*)(cur + 16384 + row * 64 + blk * 16);
        }
        #pragma unroll
        for (int mt = 0; mt < 8; ++mt)
            #pragma unroll
            for (int nt = 0; nt < 3; ++nt) {
                acc[mt][nt] = __builtin_amdgcn_mfma_f32_16x16x32_bf16(ah[mt], bh[nt], acc[mt][nt], 0, 0, 0);
                acc[mt][nt] = __builtin_amdgcn_mfma_f32_16x16x32_bf16(ah[mt], bl[nt], acc[mt][nt], 0, 0, 0);
                acc[mt][nt] = __builtin_amdgcn_mfma_f32_16x16x32_bf16(al[mt], bh[nt], acc[mt][nt], 0, 0, 0);
            }
        __syncthreads();
    }

    // ---- sims -> LDS overlay (already / TEMPERATURE); col-XOR bank swizzle
    #pragma unroll
    for (int mt = 0; mt < 8; ++mt)
        #pragma unroll
        for (int nt = 0; nt < 3; ++nt) {
            const int col = wn * 48 + nt * 16 + l15;
            #pragma unroll
            for (int reg = 0; reg < 4; ++reg) {
                const int row = wm * 128 + mt * 16 + (lane >> 4) * 4 + reg;
                sS[row * 144 + (col ^ ((row >> 1) & 15))] = acc[mt][nt][reg] * 10.f;
            }
        }
    __syncthreads();

    // ---- postprocess: 1024 tasks = 256 (cap,w) pairs x 4 images
    for (int task = t; task < 1024; task += 384) {
        const int pair = task & 255;
        const int j = task >> 8;        // image within tile
        const int qq = pair >> 5, w = pair & 31;
        const int c = cg8 * 8 + qq;
        const int i = g * 4 + j;
        float result = -1.0f;
        if (w < cap_lens[c]) {
            const int ilen = img_lens[i];   // >= 6 by construction
            const float* rowp = sS + pair * 144;
            const int xv = (pair >> 1) & 15;
            const int cb = j * 36;
            float t0 = NEGV, t1 = NEGV, t2 = NEGV, t3 = NEGV, t4 = NEGV;
            for (int r = 0; r < ilen; ++r) {
                const float v = rowp[(cb + r) ^ xv];
                if (v > t4) {
                    if (v > t0)      { t4=t3; t3=t2; t2=t1; t1=t0; t0=v; }
                    else if (v > t1) { t4=t3; t3=t2; t2=t1; t1=v; }
                    else if (v > t2) { t4=t3; t3=t2; t2=v; }
                    else if (v > t3) { t4=t3; t3=v; }
                    else             { t4=v; }
                }
            }
            const float kth = t4, m = t0;
            int   idxs[8];
            float pv[8];
            int cnt = 0;
            float sum = 0.f;
            for (int r = 0; r < ilen; ++r) {
                const float v = rowp[(cb + r) ^ xv];
                if (v >= kth) {
                    const float e = expf(v - m);
                    sum += e;
                    if (cnt < 8) { idxs[cnt] = r; pv[cnt] = e; ++cnt; }
                }
            }
            const float inv = 1.0f / sum;
            const __half* gj = sG + j * 1296;
            float num = 0.f, den2 = 0.f;
            for (int a = 0; a < cnt; ++a) {
                const float pa = pv[a] * inv;
                num += pa * rowp[(cb + idxs[a]) ^ xv];
                for (int b = 0; b < cnt; ++b)
                    den2 += pa * (pv[b] * inv) * __half2float(gj[idxs[a] * 36 + idxs[b]]);
            }
            num *= 0.1f;
            const float den = sqrtf(den2) + (-1e-8f);
            result = num / den;
        }
        out[((size_t)i * N_CAP + c) * MAX_W + w] = result;
    }
}

extern "C" void kernel_launch(void* const* d_in, const int* in_sizes, int n_in,
                              void* d_out, int out_size, void* d_ws, size_t ws_size,
                              hipStream_t stream) {
    const float* imgs     = (const float*)d_in[0];
    const float* caps     = (const float*)d_in[1];
    const int*   img_lens = (const int*)d_in[2];
    const int*   cap_lens = (const int*)d_in[3];
    float* out = (float*)d_out;

    // d_ws layout
    __half* G16 = (__half*)d_ws;                               // 128*1296*2 = 331776 B
    u16* imgsT = (u16*)((char*)d_ws + 331776);                 // 32*16*9216 u16 = 9437184 B
    u16* capsT = imgsT + (size_t)32 * 16 * B_CHUNK_U16;        // 16*16*16384 u16 = 8388608 B

    hipFuncSetAttribute((const void*)vsc_mfma_kernel,
                        hipFuncAttributeMaxDynamicSharedMemorySize, LDS_BYTES);

    convert_kernel<<<2048, 256, 0, stream>>>(imgs, caps, imgsT, capsT);
    gram_kernel<<<N_IMG, 256, 0, stream>>>(imgs, G16);
    vsc_mfma_kernel<<<512, 384, LDS_BYTES, stream>>>(imgsT, capsT, img_lens, cap_lens, G16, out);
}

// Round 9
// 114.259 us; speedup vs baseline: 1.6402x; 1.3141x over previous
//
#include <hip/hip_runtime.h>
#include <cmath>

#define N_IMG 128
#define MAX_R 36
#define N_CAP 128
#define MAX_W 32
#define DIM   512
#define NEGV  -1e30f

typedef unsigned short u16;
typedef unsigned int   u32;
typedef unsigned char  u8;
typedef __attribute__((ext_vector_type(4))) int i32x4;

#define NI_ELEMS (N_IMG * MAX_R * DIM)   // 2359296
#define NC_ELEMS (N_CAP * MAX_W * DIM)   // 2097152

// i8 chunk geometry (bytes)
#define A_CHUNK 18432   // imgs per (g,kb):  [h 144x64][l 144x64]
#define B_CHUNK 16384   // caps per (cg,kb): [h 128x64][l 128x64]
#define BUF_BYTES 34816 // A + B per K-step
#define LDS_BYTES 69632 // double buffer; 2 blocks/CU

__device__ __forceinline__ void gload_lds16(const void* g, void* l) {
    __builtin_amdgcn_global_load_lds(
        (const __attribute__((address_space(1))) void*)g,
        (__attribute__((address_space(3))) void*)l, 16, 0, 0);
}

// ---------------------------------------------------------------------------
// Kernel 0: fp32 -> i16 -> (h,l) i8 split, pre-tiled + pre-swizzled.
// x ~= 2^-12 * (256*h + l). imgs packed 144 rows/tile (no pad), caps 128 rows.
// ---------------------------------------------------------------------------
__global__ __launch_bounds__(256) void convert_kernel(const float* __restrict__ imgs,
                                                      const float* __restrict__ caps,
                                                      u8* __restrict__ imgsT,
                                                      u8* __restrict__ capsT) {
    const size_t ni4 = NI_ELEMS / 4;
    const size_t total4 = (NI_ELEMS + NC_ELEMS) / 4;
    const size_t stride = (size_t)gridDim.x * blockDim.x;
    for (size_t p = (size_t)blockIdx.x * blockDim.x + threadIdx.x; p < total4; p += stride) {
        const bool isImg = p < ni4;
        const float4 v = isImg ? ((const float4*)imgs)[p] : ((const float4*)caps)[p - ni4];
        const int q0 = (int)rintf(fminf(fmaxf(v.x * 4096.f, -32639.f), 32639.f));
        const int q1 = (int)rintf(fminf(fmaxf(v.y * 4096.f, -32639.f), 32639.f));
        const int q2 = (int)rintf(fminf(fmaxf(v.z * 4096.f, -32639.f), 32639.f));
        const int q3 = (int)rintf(fminf(fmaxf(v.w * 4096.f, -32639.f), 32639.f));
        const int h0 = (q0 + 128) >> 8, l0 = q0 - (h0 << 8);
        const int h1 = (q1 + 128) >> 8, l1 = q1 - (h1 << 8);
        const int h2 = (q2 + 128) >> 8, l2 = q2 - (h2 << 8);
        const int h3 = (q3 + 128) >> 8, l3 = q3 - (h3 << 8);
        const u32 hw = (u32)(h0 & 255) | ((u32)(h1 & 255) << 8) |
                       ((u32)(h2 & 255) << 16) | ((u32)(h3 & 255) << 24);
        const u32 lw = (u32)(l0 & 255) | ((u32)(l1 & 255) << 8) |
                       ((u32)(l2 & 255) << 16) | ((u32)(l3 & 255) << 24);
        if (isImg) {
            const int e = (int)(p * 4);
            const int imgRow = e >> 9, k = e & 511;
            const int g = imgRow / 144;
            const int rowT = imgRow - g * 144;
            const int kb = k >> 6, k6 = k & 63;
            const int blk = (k6 >> 4) ^ ((rowT >> 1) & 3);
            const size_t off = (size_t)(g * 8 + kb) * A_CHUNK + rowT * 64 + blk * 16 + (k6 & 15);
            *(u32*)(imgsT + off) = hw;
            *(u32*)(imgsT + off + 9216) = lw;
        } else {
            const int e = (int)((p - ni4) * 4);
            const int R = e >> 9, k = e & 511;
            const int cg = R >> 7, row = R & 127;
            const int kb = k >> 6, k6 = k & 63;
            const int blk = (k6 >> 4) ^ ((row >> 1) & 3);
            const size_t off = (size_t)(cg * 8 + kb) * B_CHUNK + row * 64 + blk * 16 + (k6 & 15);
            *(u32*)(capsT + off) = hw;
            *(u32*)(capsT + off + 8192) = lw;
        }
    }
}

// ---------------------------------------------------------------------------
// Kernel A: per-image Gram matrices (fp32): G[i][a*36+b] = dot(img_a, img_b)
// ---------------------------------------------------------------------------
__global__ __launch_bounds__(256) void gram_kernel(const float* __restrict__ imgs,
                                                   float* __restrict__ G) {
    const int i = blockIdx.x;
    const int t = threadIdx.x;
    __shared__ float sImg[MAX_R][132];
    const float* base = imgs + (size_t)i * MAX_R * DIM;

    const int ap = t / 12;
    const int bt = t % 12;
    const bool active = ap < 18;
    float acc[2][3] = {};

    for (int ch = 0; ch < 4; ++ch) {
        for (int idx = t; idx < MAX_R * 32; idx += 256) {
            const int row = idx >> 5, col = idx & 31;
            *(float4*)&sImg[row][col * 4] =
                *(const float4*)(base + row * DIM + ch * 128 + col * 4);
        }
        __syncthreads();
        if (active) {
            #pragma unroll
            for (int k4 = 0; k4 < 32; ++k4) {
                float4 a0 = *(float4*)&sImg[ap * 2 + 0][k4 * 4];
                float4 a1 = *(float4*)&sImg[ap * 2 + 1][k4 * 4];
                float4 b0 = *(float4*)&sImg[bt * 3 + 0][k4 * 4];
                float4 b1 = *(float4*)&sImg[bt * 3 + 1][k4 * 4];
                float4 b2 = *(float4*)&sImg[bt * 3 + 2][k4 * 4];
                acc[0][0] += a0.x*b0.x + a0.y*b0.y + a0.z*b0.z + a0.w*b0.w;
                acc[0][1] += a0.x*b1.x + a0.y*b1.y + a0.z*b1.z + a0.w*b1.w;
                acc[0][2] += a0.x*b2.x + a0.y*b2.y + a0.z*b2.z + a0.w*b2.w;
                acc[1][0] += a1.x*b0.x + a1.y*b0.y + a1.z*b0.z + a1.w*b0.w;
                acc[1][1] += a1.x*b1.x + a1.y*b1.y + a1.z*b1.z + a1.w*b1.w;
                acc[1][2] += a1.x*b2.x + a1.y*b2.y + a1.z*b2.z + a1.w*b2.w;
            }
        }
        __syncthreads();
    }
    if (active) {
        float* g = G + (size_t)i * (MAX_R * MAX_R);
        #pragma unroll
        for (int x = 0; x < 2; ++x)
            #pragma unroll
            for (int y = 0; y < 3; ++y)
                g[(ap * 2 + x) * MAX_R + (bt * 3 + y)] = acc[x][y];
    }
}

// ---------------------------------------------------------------------------
// Kernel B: block = 4 images (144 packed M-rows) x 4 caps (128 N-cols).
// 4 waves, wave = 144x32 (mt=9, nt=2). i8 EXACT split MFMA (16x16x64):
// accH=h*h, accC=h*l+l*h, accL=l*l -> S = 10*2^-24*(65536 HH + 256 CR + LL).
// (R8 failed at 0.14 absmax from dropping LL: sigma 0.074 s-units.)
// Register epilogue: top-5 + softmax + Gram den2, no sS round-trip.
// ---------------------------------------------------------------------------
__global__ __launch_bounds__(256, 2) void vsc_mfma_kernel(const u8* __restrict__ imgsT,
                                const u8* __restrict__ capsT,
                                const int* __restrict__ img_lens,
                                const int* __restrict__ cap_lens,
                                const float* __restrict__ G,
                                float* __restrict__ out) {
    extern __shared__ __align__(16) char smem[];
    const int bid = blockIdx.x;
    const int xcd = bid & 7;
    const int r_  = bid >> 3;
    const int g   = (r_ >> 5) * 8 + xcd;   // image tile 0..31 (4 imgs)
    const int cg  = r_ & 31;               // cap group 0..31 (4 caps = 128 rows)
    const int t = threadIdx.x;
    const int wid = t >> 6;                // 0..3
    const int lane = t & 63;
    const int l15 = lane & 15;
    const int kblk = lane >> 4;            // also the epilogue quad index

    const u8* gA = imgsT + (size_t)g * 8 * A_CHUNK;
    const u8* gB = capsT + (size_t)cg * 8 * B_CHUNK;

    auto stage = [&](int kb, char* buf) {
        if (wid < 2) {           // A (imgs): 18432 B, 2 waves x 9 KB
            const u8* src = gA + (size_t)kb * A_CHUNK + wid * 9216 + lane * 16;
            char* dst = buf + wid * 9216;
            #pragma unroll
            for (int jj = 0; jj < 9; ++jj)
                gload_lds16(src + jj * 1024, dst + jj * 1024);
        } else {                 // B (caps): 16384 B, 2 waves x 8 KB
            const int wb = wid - 2;
            const u8* src = gB + (size_t)kb * B_CHUNK + wb * 8192 + lane * 16;
            char* dst = buf + 18432 + wb * 8192;
            #pragma unroll
            for (int jj = 0; jj < 8; ++jj)
                gload_lds16(src + jj * 1024, dst + jj * 1024);
        }
    };

    i32x4 accH[9][2], accC[9][2], accL[9][2];
    #pragma unroll
    for (int mt = 0; mt < 9; ++mt)
        #pragma unroll
        for (int nt = 0; nt < 2; ++nt) {
            accH[mt][nt] = (i32x4){0, 0, 0, 0};
            accC[mt][nt] = (i32x4){0, 0, 0, 0};
            accL[mt][nt] = (i32x4){0, 0, 0, 0};
        }

    stage(0, smem);
    __syncthreads();

    const int blk16 = (kblk ^ ((l15 >> 1) & 3)) << 4;
    const int baseA = l15 * 64 + blk16;                // + mt*1024 ; h: +0, l: +9216
    const int baseB = (wid * 32 + l15) * 64 + blk16;   // + nt*1024 ; h: +18432, l: +26624

    for (int kb = 0; kb < 8; ++kb) {
        char* cur = smem + (size_t)(kb & 1) * BUF_BYTES;
        if (kb < 7) stage(kb + 1, smem + (size_t)((kb + 1) & 1) * BUF_BYTES);

        const i32x4 bh0 = *(const i32x4*)(cur + 18432 + baseB);
        const i32x4 bl0 = *(const i32x4*)(cur + 26624 + baseB);
        const i32x4 bh1 = *(const i32x4*)(cur + 18432 + baseB + 1024);
        const i32x4 bl1 = *(const i32x4*)(cur + 26624 + baseB + 1024);
        #pragma unroll
        for (int mt = 0; mt < 9; ++mt) {
            const i32x4 ah = *(const i32x4*)(cur + baseA + mt * 1024);
            const i32x4 al = *(const i32x4*)(cur + 9216 + baseA + mt * 1024);
            accH[mt][0] = __builtin_amdgcn_mfma_i32_16x16x64_i8(ah, bh0, accH[mt][0], 0, 0, 0);
            accC[mt][0] = __builtin_amdgcn_mfma_i32_16x16x64_i8(ah, bl0, accC[mt][0], 0, 0, 0);
            accC[mt][0] = __builtin_amdgcn_mfma_i32_16x16x64_i8(al, bh0, accC[mt][0], 0, 0, 0);
            accL[mt][0] = __builtin_amdgcn_mfma_i32_16x16x64_i8(al, bl0, accL[mt][0], 0, 0, 0);
            accH[mt][1] = __builtin_amdgcn_mfma_i32_16x16x64_i8(ah, bh1, accH[mt][1], 0, 0, 0);
            accC[mt][1] = __builtin_amdgcn_mfma_i32_16x16x64_i8(ah, bl1, accC[mt][1], 0, 0, 0);
            accC[mt][1] = __builtin_amdgcn_mfma_i32_16x16x64_i8(al, bh1, accC[mt][1], 0, 0, 0);
            accL[mt][1] = __builtin_amdgcn_mfma_i32_16x16x64_i8(al, bl1, accL[mt][1], 0, 0, 0);
        }
        __syncthreads();
    }

    // ---- fold: S = sims/T  (all three integers f32-exact: <2^24)
    float sv[9][2][4];
    #pragma unroll
    for (int mt = 0; mt < 9; ++mt)
        #pragma unroll
        for (int nt = 0; nt < 2; ++nt)
            #pragma unroll
            for (int e = 0; e < 4; ++e)
                sv[mt][nt][e] = (float)accH[mt][nt][e] * (10.f / 256.f)
                              + (float)accC[mt][nt][e] * (10.f / 65536.f)
                              + (float)accL[mt][nt][e] * (10.f / 16777216.f);

    // ---- stage Gram (4 imgs, fp32) into retired staging LDS
    float* sG = (float*)smem;
    {
        const float4* src = (const float4*)(G + (size_t)g * 4 * 1296);
        for (int idx = t; idx < 1296; idx += 256)
            ((float4*)sG)[idx] = src[idx];
    }
    __syncthreads();

    int ilen_[4];
    #pragma unroll
    for (int j = 0; j < 4; ++j) ilen_[j] = img_lens[g * 4 + j];

    #pragma unroll
    for (int nt = 0; nt < 2; ++nt) {
        const int col = wid * 32 + nt * 16 + l15;     // 0..127 cap-word col
        const int c = cg * 4 + (col >> 5);
        const int w = col & 31;
        const int clen = cap_lens[c];
        #pragma unroll
        for (int j = 0; j < 4; ++j) {
            const int mtb = (36 * j) >> 4;            // 0,2,4,6
            const int ilenj = ilen_[j];
            // branchless local top-5 over this lane's rows of img j (rr in bits 0..5)
            float tv0 = NEGV, tv1 = NEGV, tv2 = NEGV, tv3 = NEGV, tv4 = NEGV;
            #pragma unroll
            for (int dm = 0; dm < 3; ++dm) {
                #pragma unroll
                for (int e = 0; e < 4; ++e) {
                    const int mt = mtb + dm;
                    const int r = mt * 16 + kblk * 4 + e;
                    const int rr = r - 36 * j;
                    float v = NEGV;
                    if ((unsigned)rr < (unsigned)ilenj)
                        v = __uint_as_float((__float_as_uint(sv[mt][nt][e]) & ~63u) | (u32)rr);
                    const bool c0 = v > tv0, c1 = v > tv1, c2 = v > tv2, c3 = v > tv3, c4 = v > tv4;
                    const float n4 = c4 ? (c3 ? tv3 : v) : tv4;
                    const float n3 = c3 ? (c2 ? tv2 : v) : tv3;
                    const float n2 = c2 ? (c1 ? tv1 : v) : tv2;
                    const float n1 = c1 ? (c0 ? tv0 : v) : tv1;
                    const float n0 = c0 ? v : tv0;
                    tv0 = n0; tv1 = n1; tv2 = n2; tv3 = n3; tv4 = n4;
                }
            }
            // 2-step butterfly sorted-merge across the 4-lane quad (lane^16, lane^32)
            float ta[5] = {tv0, tv1, tv2, tv3, tv4};
            #pragma unroll
            for (int st = 0; st < 2; ++st) {
                const int dx = 16 << st;
                float tb[5];
                #pragma unroll
                for (int s = 0; s < 5; ++s) tb[s] = __shfl_xor(ta[s], dx);
                float na[5];
                #pragma unroll
                for (int k = 0; k < 5; ++k) {
                    float best = fmaxf(ta[k], tb[k]);
                    #pragma unroll
                    for (int i2 = 1; i2 <= k; ++i2)
                        best = fmaxf(best, fminf(ta[i2 - 1], tb[k - i2]));
                    na[k] = best;
                }
                #pragma unroll
                for (int s = 0; s < 5; ++s) ta[s] = na[s];
            }
            // softmax over the 5
            const float m = ta[0];
            const float p0 = 1.f;
            const float p1 = expf(ta[1] - m);
            const float p2 = expf(ta[2] - m);
            const float p3 = expf(ta[3] - m);
            const float p4 = expf(ta[4] - m);
            const float sum = p0 + p1 + p2 + p3 + p4;
            const float num = p0 * ta[0] + p1 * ta[1] + p2 * ta[2] + p3 * ta[3] + p4 * ta[4];
            const int r0 = __float_as_uint(ta[0]) & 63;
            const int r1 = __float_as_uint(ta[1]) & 63;
            const int r2 = __float_as_uint(ta[2]) & 63;
            const int r3 = __float_as_uint(ta[3]) & 63;
            const int r4 = __float_as_uint(ta[4]) & 63;
            const float* gj = sG + j * 1296;
            // den2 = sum_{a,b} p_a p_b G[ra][rb]; a-rows split across the quad
            const float pa = (kblk == 0) ? p0 : (kblk == 1) ? p1 : (kblk == 2) ? p2 : p3;
            const int   ra = (kblk == 0) ? r0 : (kblk == 1) ? r1 : (kblk == 2) ? r2 : r3;
            const float* grow = gj + ra * 36;
            float part = pa * (p0 * grow[r0] + p1 * grow[r1] + p2 * grow[r2]
                             + p3 * grow[r3] + p4 * grow[r4]);
            if (kblk == 0) {
                const float* grow4 = gj + r4 * 36;
                part += p4 * (p0 * grow4[r0] + p1 * grow4[r1] + p2 * grow4[r2]
                            + p3 * grow4[r3] + p4 * grow4[r4]);
            }
            part += __shfl_xor(part, 16);
            part += __shfl_xor(part, 32);
            if (kblk == j) {
                float result = -1.f;
                if (w < clen) {
                    const float inv = 1.f / sum;
                    const float a_ = 0.1f * num * inv;
                    const float den = sqrtf(part) * inv + (-1e-8f);
                    result = a_ / den;
                }
                out[((size_t)(g * 4 + j) * N_CAP + c) * MAX_W + w] = result;
            }
        }
    }
}

extern "C" void kernel_launch(void* const* d_in, const int* in_sizes, int n_in,
                              void* d_out, int out_size, void* d_ws, size_t ws_size,
                              hipStream_t stream) {
    const float* imgs     = (const float*)d_in[0];
    const float* caps     = (const float*)d_in[1];
    const int*   img_lens = (const int*)d_in[2];
    const int*   cap_lens = (const int*)d_in[3];
    float* out = (float*)d_out;

    // d_ws layout
    float* G  = (float*)d_ws;                          // 128*1296*4 = 663552 B
    u8* imgsT = (u8*)d_ws + 663552;                    // 32*8*18432 = 4718592 B
    u8* capsT = imgsT + (size_t)32 * 8 * A_CHUNK;      // 32*8*16384 = 4194304 B

    hipFuncSetAttribute((const void*)vsc_mfma_kernel,
                        hipFuncAttributeMaxDynamicSharedMemorySize, LDS_BYTES);

    convert_kernel<<<2048, 256, 0, stream>>>(imgs, caps, imgsT, capsT);
    gram_kernel<<<N_IMG, 256, 0, stream>>>(imgs, G);
    vsc_mfma_kernel<<<1024, 256, LDS_BYTES, stream>>>(imgsT, capsT, img_lens, cap_lens, G, out);
}

// Round 10
// 94.329 us; speedup vs baseline: 1.9867x; 1.2113x over previous
//
#include <hip/hip_runtime.h>
#include <cmath>

#define N_IMG 128
#define MAX_R 36
#define N_CAP 128
#define MAX_W 32
#define DIM   512
#define NEGV  -1e30f

typedef unsigned short u16;
typedef unsigned int   u32;
typedef unsigned char  u8;
typedef __attribute__((ext_vector_type(4))) int i32x4;

#define NI_ELEMS (N_IMG * MAX_R * DIM)   // 2359296
#define NC_ELEMS (N_CAP * MAX_W * DIM)   // 2097152

// i8 chunk geometry (bytes)
#define A_CHUNK 18432   // imgs per (g,kb):  [h 144x64][l 144x64]
#define B_CHUNK 16384   // caps per (cg,kb): [h 128x64][l 128x64]
#define BUF_BYTES 34816 // A + B per K-step
#define LDS_BYTES 69632 // double buffer; 2 blocks/CU

__device__ __forceinline__ void gload_lds16(const void* g, void* l) {
    __builtin_amdgcn_global_load_lds(
        (const __attribute__((address_space(1))) void*)g,
        (__attribute__((address_space(3))) void*)l, 16, 0, 0);
}

// ---------------------------------------------------------------------------
// Kernel 0: fp32 -> i16 -> (h,l) i8 split, pre-tiled + pre-swizzled.
// x ~= 2^-12 * (256*h + l). imgs packed 144 rows/tile (no pad), caps 128 rows.
// ---------------------------------------------------------------------------
__global__ __launch_bounds__(256) void convert_kernel(const float* __restrict__ imgs,
                                                      const float* __restrict__ caps,
                                                      u8* __restrict__ imgsT,
                                                      u8* __restrict__ capsT) {
    const size_t ni4 = NI_ELEMS / 4;
    const size_t total4 = (NI_ELEMS + NC_ELEMS) / 4;
    const size_t stride = (size_t)gridDim.x * blockDim.x;
    for (size_t p = (size_t)blockIdx.x * blockDim.x + threadIdx.x; p < total4; p += stride) {
        const bool isImg = p < ni4;
        const float4 v = isImg ? ((const float4*)imgs)[p] : ((const float4*)caps)[p - ni4];
        const int q0 = (int)rintf(fminf(fmaxf(v.x * 4096.f, -32639.f), 32639.f));
        const int q1 = (int)rintf(fminf(fmaxf(v.y * 4096.f, -32639.f), 32639.f));
        const int q2 = (int)rintf(fminf(fmaxf(v.z * 4096.f, -32639.f), 32639.f));
        const int q3 = (int)rintf(fminf(fmaxf(v.w * 4096.f, -32639.f), 32639.f));
        const int h0 = (q0 + 128) >> 8, l0 = q0 - (h0 << 8);
        const int h1 = (q1 + 128) >> 8, l1 = q1 - (h1 << 8);
        const int h2 = (q2 + 128) >> 8, l2 = q2 - (h2 << 8);
        const int h3 = (q3 + 128) >> 8, l3 = q3 - (h3 << 8);
        const u32 hw = (u32)(h0 & 255) | ((u32)(h1 & 255) << 8) |
                       ((u32)(h2 & 255) << 16) | ((u32)(h3 & 255) << 24);
        const u32 lw = (u32)(l0 & 255) | ((u32)(l1 & 255) << 8) |
                       ((u32)(l2 & 255) << 16) | ((u32)(l3 & 255) << 24);
        if (isImg) {
            const int e = (int)(p * 4);
            const int imgRow = e >> 9, k = e & 511;
            const int g = imgRow / 144;
            const int rowT = imgRow - g * 144;
            const int kb = k >> 6, k6 = k & 63;
            const int blk = (k6 >> 4) ^ ((rowT >> 1) & 3);
            const size_t off = (size_t)(g * 8 + kb) * A_CHUNK + rowT * 64 + blk * 16 + (k6 & 15);
            *(u32*)(imgsT + off) = hw;
            *(u32*)(imgsT + off + 9216) = lw;
        } else {
            const int e = (int)((p - ni4) * 4);
            const int R = e >> 9, k = e & 511;
            const int cg = R >> 7, row = R & 127;
            const int kb = k >> 6, k6 = k & 63;
            const int blk = (k6 >> 4) ^ ((row >> 1) & 3);
            const size_t off = (size_t)(cg * 8 + kb) * B_CHUNK + row * 64 + blk * 16 + (k6 & 15);
            *(u32*)(capsT + off) = hw;
            *(u32*)(capsT + off + 8192) = lw;
        }
    }
}

// ---------------------------------------------------------------------------
// Kernel A: per-image Gram matrices (fp32): G[i][a*36+b] = dot(img_a, img_b)
// ---------------------------------------------------------------------------
__global__ __launch_bounds__(256) void gram_kernel(const float* __restrict__ imgs,
                                                   float* __restrict__ G) {
    const int i = blockIdx.x;
    const int t = threadIdx.x;
    __shared__ float sImg[MAX_R][132];
    const float* base = imgs + (size_t)i * MAX_R * DIM;

    const int ap = t / 12;
    const int bt = t % 12;
    const bool active = ap < 18;
    float acc[2][3] = {};

    for (int ch = 0; ch < 4; ++ch) {
        for (int idx = t; idx < MAX_R * 32; idx += 256) {
            const int row = idx >> 5, col = idx & 31;
            *(float4*)&sImg[row][col * 4] =
                *(const float4*)(base + row * DIM + ch * 128 + col * 4);
        }
        __syncthreads();
        if (active) {
            #pragma unroll
            for (int k4 = 0; k4 < 32; ++k4) {
                float4 a0 = *(float4*)&sImg[ap * 2 + 0][k4 * 4];
                float4 a1 = *(float4*)&sImg[ap * 2 + 1][k4 * 4];
                float4 b0 = *(float4*)&sImg[bt * 3 + 0][k4 * 4];
                float4 b1 = *(float4*)&sImg[bt * 3 + 1][k4 * 4];
                float4 b2 = *(float4*)&sImg[bt * 3 + 2][k4 * 4];
                acc[0][0] += a0.x*b0.x + a0.y*b0.y + a0.z*b0.z + a0.w*b0.w;
                acc[0][1] += a0.x*b1.x + a0.y*b1.y + a0.z*b1.z + a0.w*b1.w;
                acc[0][2] += a0.x*b2.x + a0.y*b2.y + a0.z*b2.z + a0.w*b2.w;
                acc[1][0] += a1.x*b0.x + a1.y*b0.y + a1.z*b0.z + a1.w*b0.w;
                acc[1][1] += a1.x*b1.x + a1.y*b1.y + a1.z*b1.z + a1.w*b1.w;
                acc[1][2] += a1.x*b2.x + a1.y*b2.y + a1.z*b2.z + a1.w*b2.w;
            }
        }
        __syncthreads();
    }
    if (active) {
        float* g = G + (size_t)i * (MAX_R * MAX_R);
        #pragma unroll
        for (int x = 0; x < 2; ++x)
            #pragma unroll
            for (int y = 0; y < 3; ++y)
                g[(ap * 2 + x) * MAX_R + (bt * 3 + y)] = acc[x][y];
    }
}

// ---------------------------------------------------------------------------
// Kernel B: block = 4 images (144 packed M-rows) x 4 caps (128 N-cols).
// 4 waves, wave = 144x32 (mt=9, nt=2). i8 EXACT split MFMA (16x16x64).
// R9 lesson: 3 persistent acc sets (216 regs) + sv[72] spilled (146MB scratch).
// Now: accH + accC persistent (144 regs); LL computed into a per-(mt,kb)
// TEMP acc and folded into accC as (lt+128)>>8 (err ~6e-4 s-units, exact
// bounds preserved: |accC| <= 9.6e6+11k < 2^24). Epilogue folds H,C inline
// at the point of use -- no sv array.
// ---------------------------------------------------------------------------
__global__ __launch_bounds__(256, 2) void vsc_mfma_kernel(const u8* __restrict__ imgsT,
                                const u8* __restrict__ capsT,
                                const int* __restrict__ img_lens,
                                const int* __restrict__ cap_lens,
                                const float* __restrict__ G,
                                float* __restrict__ out) {
    extern __shared__ __align__(16) char smem[];
    const int bid = blockIdx.x;
    const int xcd = bid & 7;
    const int r_  = bid >> 3;
    const int g   = (r_ >> 5) * 8 + xcd;   // image tile 0..31 (4 imgs)
    const int cg  = r_ & 31;               // cap group 0..31 (4 caps = 128 rows)
    const int t = threadIdx.x;
    const int wid = t >> 6;                // 0..3
    const int lane = t & 63;
    const int l15 = lane & 15;
    const int kblk = lane >> 4;            // also the epilogue quad index

    const u8* gA = imgsT + (size_t)g * 8 * A_CHUNK;
    const u8* gB = capsT + (size_t)cg * 8 * B_CHUNK;

    auto stage = [&](int kb, char* buf) {
        if (wid < 2) {           // A (imgs): 18432 B, 2 waves x 9 KB
            const u8* src = gA + (size_t)kb * A_CHUNK + wid * 9216 + lane * 16;
            char* dst = buf + wid * 9216;
            #pragma unroll
            for (int jj = 0; jj < 9; ++jj)
                gload_lds16(src + jj * 1024, dst + jj * 1024);
        } else {                 // B (caps): 16384 B, 2 waves x 8 KB
            const int wb = wid - 2;
            const u8* src = gB + (size_t)kb * B_CHUNK + wb * 8192 + lane * 16;
            char* dst = buf + 18432 + wb * 8192;
            #pragma unroll
            for (int jj = 0; jj < 8; ++jj)
                gload_lds16(src + jj * 1024, dst + jj * 1024);
        }
    };

    i32x4 accH[9][2], accC[9][2];
    #pragma unroll
    for (int mt = 0; mt < 9; ++mt)
        #pragma unroll
        for (int nt = 0; nt < 2; ++nt) {
            accH[mt][nt] = (i32x4){0, 0, 0, 0};
            accC[mt][nt] = (i32x4){0, 0, 0, 0};
        }

    stage(0, smem);
    __syncthreads();

    const int blk16 = (kblk ^ ((l15 >> 1) & 3)) << 4;
    const int baseA = l15 * 64 + blk16;                // + mt*1024 ; h: +0, l: +9216
    const int baseB = (wid * 32 + l15) * 64 + blk16;   // + nt*1024 ; h: +18432, l: +26624

    for (int kb = 0; kb < 8; ++kb) {
        char* cur = smem + (size_t)(kb & 1) * BUF_BYTES;
        if (kb < 7) stage(kb + 1, smem + (size_t)((kb + 1) & 1) * BUF_BYTES);

        const i32x4 bh0 = *(const i32x4*)(cur + 18432 + baseB);
        const i32x4 bl0 = *(const i32x4*)(cur + 26624 + baseB);
        const i32x4 bh1 = *(const i32x4*)(cur + 18432 + baseB + 1024);
        const i32x4 bl1 = *(const i32x4*)(cur + 26624 + baseB + 1024);
        #pragma unroll
        for (int mt = 0; mt < 9; ++mt) {
            const i32x4 ah = *(const i32x4*)(cur + baseA + mt * 1024);
            const i32x4 al = *(const i32x4*)(cur + 9216 + baseA + mt * 1024);
            accH[mt][0] = __builtin_amdgcn_mfma_i32_16x16x64_i8(ah, bh0, accH[mt][0], 0, 0, 0);
            accH[mt][1] = __builtin_amdgcn_mfma_i32_16x16x64_i8(ah, bh1, accH[mt][1], 0, 0, 0);
            accC[mt][0] = __builtin_amdgcn_mfma_i32_16x16x64_i8(ah, bl0, accC[mt][0], 0, 0, 0);
            accC[mt][0] = __builtin_amdgcn_mfma_i32_16x16x64_i8(al, bh0, accC[mt][0], 0, 0, 0);
            accC[mt][1] = __builtin_amdgcn_mfma_i32_16x16x64_i8(ah, bl1, accC[mt][1], 0, 0, 0);
            accC[mt][1] = __builtin_amdgcn_mfma_i32_16x16x64_i8(al, bh1, accC[mt][1], 0, 0, 0);
            i32x4 lt0 = (i32x4){0, 0, 0, 0};
            i32x4 lt1 = (i32x4){0, 0, 0, 0};
            lt0 = __builtin_amdgcn_mfma_i32_16x16x64_i8(al, bl0, lt0, 0, 0, 0);
            lt1 = __builtin_amdgcn_mfma_i32_16x16x64_i8(al, bl1, lt1, 0, 0, 0);
            #pragma unroll
            for (int e = 0; e < 4; ++e) {
                accC[mt][0][e] += (lt0[e] + 128) >> 8;
                accC[mt][1][e] += (lt1[e] + 128) >> 8;
            }
        }
        __syncthreads();
    }

    // ---- stage Gram (4 imgs, fp32) into retired staging LDS
    float* sG = (float*)smem;
    {
        const float4* src = (const float4*)(G + (size_t)g * 4 * 1296);
        for (int idx = t; idx < 1296; idx += 256)
            ((float4*)sG)[idx] = src[idx];
    }
    __syncthreads();

    int ilen_[4];
    #pragma unroll
    for (int j = 0; j < 4; ++j) ilen_[j] = img_lens[g * 4 + j];

    #pragma unroll
    for (int nt = 0; nt < 2; ++nt) {
        const int col = wid * 32 + nt * 16 + l15;     // 0..127 cap-word col
        const int c = cg * 4 + (col >> 5);
        const int w = col & 31;
        const int clen = cap_lens[c];
        #pragma unroll
        for (int j = 0; j < 4; ++j) {
            const int mtb = (36 * j) >> 4;            // 0,2,4,6
            const int ilenj = ilen_[j];
            // branchless local top-5 over this lane's rows of img j (rr in bits 0..5)
            float tv0 = NEGV, tv1 = NEGV, tv2 = NEGV, tv3 = NEGV, tv4 = NEGV;
            #pragma unroll
            for (int dm = 0; dm < 3; ++dm) {
                #pragma unroll
                for (int e = 0; e < 4; ++e) {
                    const int mt = mtb + dm;
                    const int r = mt * 16 + kblk * 4 + e;
                    const int rr = r - 36 * j;
                    // inline fold: S = 10*(HH/256 + CR/65536) (CR includes LL>>8)
                    const float sval = (float)accH[mt][nt][e] * (10.f / 256.f)
                                     + (float)accC[mt][nt][e] * (10.f / 65536.f);
                    float v = NEGV;
                    if ((unsigned)rr < (unsigned)ilenj)
                        v = __uint_as_float((__float_as_uint(sval) & ~63u) | (u32)rr);
                    const bool c0 = v > tv0, c1 = v > tv1, c2 = v > tv2, c3 = v > tv3, c4 = v > tv4;
                    const float n4 = c4 ? (c3 ? tv3 : v) : tv4;
                    const float n3 = c3 ? (c2 ? tv2 : v) : tv3;
                    const float n2 = c2 ? (c1 ? tv1 : v) : tv2;
                    const float n1 = c1 ? (c0 ? tv0 : v) : tv1;
                    const float n0 = c0 ? v : tv0;
                    tv0 = n0; tv1 = n1; tv2 = n2; tv3 = n3; tv4 = n4;
                }
            }
            // 2-step butterfly sorted-merge across the 4-lane quad (lane^16, lane^32)
            float ta[5] = {tv0, tv1, tv2, tv3, tv4};
            #pragma unroll
            for (int st = 0; st < 2; ++st) {
                const int dx = 16 << st;
                float tb[5];
                #pragma unroll
                for (int s = 0; s < 5; ++s) tb[s] = __shfl_xor(ta[s], dx);
                float na[5];
                #pragma unroll
                for (int k = 0; k < 5; ++k) {
                    float best = fmaxf(ta[k], tb[k]);
                    #pragma unroll
                    for (int i2 = 1; i2 <= k; ++i2)
                        best = fmaxf(best, fminf(ta[i2 - 1], tb[k - i2]));
                    na[k] = best;
                }
                #pragma unroll
                for (int s = 0; s < 5; ++s) ta[s] = na[s];
            }
            // softmax over the 5
            const float m = ta[0];
            const float p0 = 1.f;
            const float p1 = expf(ta[1] - m);
            const float p2 = expf(ta[2] - m);
            const float p3 = expf(ta[3] - m);
            const float p4 = expf(ta[4] - m);
            const float sum = p0 + p1 + p2 + p3 + p4;
            const float num = p0 * ta[0] + p1 * ta[1] + p2 * ta[2] + p3 * ta[3] + p4 * ta[4];
            const int r0 = __float_as_uint(ta[0]) & 63;
            const int r1 = __float_as_uint(ta[1]) & 63;
            const int r2 = __float_as_uint(ta[2]) & 63;
            const int r3 = __float_as_uint(ta[3]) & 63;
            const int r4 = __float_as_uint(ta[4]) & 63;
            const float* gj = sG + j * 1296;
            // den2 = sum_{a,b} p_a p_b G[ra][rb]; a-rows split across the quad
            const float pa = (kblk == 0) ? p0 : (kblk == 1) ? p1 : (kblk == 2) ? p2 : p3;
            const int   ra = (kblk == 0) ? r0 : (kblk == 1) ? r1 : (kblk == 2) ? r2 : r3;
            const float* grow = gj + ra * 36;
            float part = pa * (p0 * grow[r0] + p1 * grow[r1] + p2 * grow[r2]
                             + p3 * grow[r3] + p4 * grow[r4]);
            if (kblk == 0) {
                const float* grow4 = gj + r4 * 36;
                part += p4 * (p0 * grow4[r0] + p1 * grow4[r1] + p2 * grow4[r2]
                            + p3 * grow4[r3] + p4 * grow4[r4]);
            }
            part += __shfl_xor(part, 16);
            part += __shfl_xor(part, 32);
            if (kblk == j) {
                float result = -1.f;
                if (w < clen) {
                    const float inv = 1.f / sum;
                    const float a_ = 0.1f * num * inv;
                    const float den = sqrtf(part) * inv + (-1e-8f);
                    result = a_ / den;
                }
                out[((size_t)(g * 4 + j) * N_CAP + c) * MAX_W + w] = result;
            }
        }
    }
}

extern "C" void kernel_launch(void* const* d_in, const int* in_sizes, int n_in,
                              void* d_out, int out_size, void* d_ws, size_t ws_size,
                              hipStream_t stream) {
    const float* imgs     = (const float*)d_in[0];
    const float* caps     = (const float*)d_in[1];
    const int*   img_lens = (const int*)d_in[2];
    const int*   cap_lens = (const int*)d_in[3];
    float* out = (float*)d_out;

    // d_ws layout
    float* G  = (float*)d_ws;                          // 128*1296*4 = 663552 B
    u8* imgsT = (u8*)d_ws + 663552;                    // 32*8*18432 = 4718592 B
    u8* capsT = imgsT + (size_t)32 * 8 * A_CHUNK;      // 32*8*16384 = 4194304 B

    hipFuncSetAttribute((const void*)vsc_mfma_kernel,
                        hipFuncAttributeMaxDynamicSharedMemorySize, LDS_BYTES);

    convert_kernel<<<2048, 256, 0, stream>>>(imgs, caps, imgsT, capsT);
    gram_kernel<<<N_IMG, 256, 0, stream>>>(imgs, G);
    vsc_mfma_kernel<<<1024, 256, LDS_BYTES, stream>>>(imgsT, capsT, img_lens, cap_lens, G, out);
}

// Round 11
// 78.698 us; speedup vs baseline: 2.3813x; 1.1986x over previous
//
#include <hip/hip_runtime.h>
#include <cmath>

#define N_IMG 128
#define MAX_R 36
#define N_CAP 128
#define MAX_W 32
#define DIM   512
#define NEGV  -1e30f

typedef unsigned short u16;
typedef unsigned int   u32;
typedef unsigned char  u8;
typedef __attribute__((ext_vector_type(4))) int i32x4;

#define NI_ELEMS (N_IMG * MAX_R * DIM)   // 2359296
#define NC_ELEMS (N_CAP * MAX_W * DIM)   // 2097152

// i8 chunk geometry (bytes)
#define A_CHUNK 18432   // imgs per (g,kb):  [h 144x64][l 144x64]
#define B_CHUNK 16384   // caps per (cg,kb): [h 128x64][l 128x64]
#define BUF_BYTES 34816 // A + B per K-step
#define LDS_BYTES 69632 // double buffer; 2 blocks/CU

__device__ __forceinline__ void gload_lds16(const void* g, void* l) {
    __builtin_amdgcn_global_load_lds(
        (const __attribute__((address_space(1))) void*)g,
        (__attribute__((address_space(3))) void*)l, 16, 0, 0);
}

// ---------------------------------------------------------------------------
// Kernel 0: fp32 -> i16 -> (h,l) i8 split, pre-tiled + pre-swizzled.
// x ~= 2^-12 * (256*h + l). imgs packed 144 rows/tile (no pad), caps 128 rows.
// ---------------------------------------------------------------------------
__global__ __launch_bounds__(256) void convert_kernel(const float* __restrict__ imgs,
                                                      const float* __restrict__ caps,
                                                      u8* __restrict__ imgsT,
                                                      u8* __restrict__ capsT) {
    const size_t ni4 = NI_ELEMS / 4;
    const size_t total4 = (NI_ELEMS + NC_ELEMS) / 4;
    const size_t stride = (size_t)gridDim.x * blockDim.x;
    for (size_t p = (size_t)blockIdx.x * blockDim.x + threadIdx.x; p < total4; p += stride) {
        const bool isImg = p < ni4;
        const float4 v = isImg ? ((const float4*)imgs)[p] : ((const float4*)caps)[p - ni4];
        const int q0 = (int)rintf(fminf(fmaxf(v.x * 4096.f, -32639.f), 32639.f));
        const int q1 = (int)rintf(fminf(fmaxf(v.y * 4096.f, -32639.f), 32639.f));
        const int q2 = (int)rintf(fminf(fmaxf(v.z * 4096.f, -32639.f), 32639.f));
        const int q3 = (int)rintf(fminf(fmaxf(v.w * 4096.f, -32639.f), 32639.f));
        const int h0 = (q0 + 128) >> 8, l0 = q0 - (h0 << 8);
        const int h1 = (q1 + 128) >> 8, l1 = q1 - (h1 << 8);
        const int h2 = (q2 + 128) >> 8, l2 = q2 - (h2 << 8);
        const int h3 = (q3 + 128) >> 8, l3 = q3 - (h3 << 8);
        const u32 hw = (u32)(h0 & 255) | ((u32)(h1 & 255) << 8) |
                       ((u32)(h2 & 255) << 16) | ((u32)(h3 & 255) << 24);
        const u32 lw = (u32)(l0 & 255) | ((u32)(l1 & 255) << 8) |
                       ((u32)(l2 & 255) << 16) | ((u32)(l3 & 255) << 24);
        if (isImg) {
            const int e = (int)(p * 4);
            const int imgRow = e >> 9, k = e & 511;
            const int g = imgRow / 144;
            const int rowT = imgRow - g * 144;
            const int kb = k >> 6, k6 = k & 63;
            const int blk = (k6 >> 4) ^ ((rowT >> 1) & 3);
            const size_t off = (size_t)(g * 8 + kb) * A_CHUNK + rowT * 64 + blk * 16 + (k6 & 15);
            *(u32*)(imgsT + off) = hw;
            *(u32*)(imgsT + off + 9216) = lw;
        } else {
            const int e = (int)((p - ni4) * 4);
            const int R = e >> 9, k = e & 511;
            const int cg = R >> 7, row = R & 127;
            const int kb = k >> 6, k6 = k & 63;
            const int blk = (k6 >> 4) ^ ((row >> 1) & 3);
            const size_t off = (size_t)(cg * 8 + kb) * B_CHUNK + row * 64 + blk * 16 + (k6 & 15);
            *(u32*)(capsT + off) = hw;
            *(u32*)(capsT + off + 8192) = lw;
        }
    }
}

// ---------------------------------------------------------------------------
// Kernel A (new): per-image Gram via i8 MFMA from imgsT (replaces the ~16us
// fp32-VALU gram). Exact 3-acc fold; G error ~2e-3 << budget. 1 block/image.
// Image i = rows [ (i%4)*36, +36 ) of chunk g=i/4. LDS tile has 48 rows;
// rows 36..47 left uninitialized -> garbage only in discarded out rows/cols.
// ---------------------------------------------------------------------------
__global__ __launch_bounds__(256) void gram_i8_kernel(const u8* __restrict__ imgsT,
                                                      float* __restrict__ G) {
    const int i  = blockIdx.x;
    const int gg = i >> 2;
    const int m  = i & 3;
    const int t = threadIdx.x;
    const int wid = t >> 6;
    const int lane = t & 63;
    const int l15 = lane & 15;
    const int kq = lane >> 4;

    __shared__ __align__(16) u8 sT[2][2][3072];   // [buf][h/l][48 rows x 64]

    const u8* base = imgsT + (size_t)gg * 8 * A_CHUNK + m * 36 * 64;

    auto stage = [&](int kb, int buf) {
        const u8* hsrc = base + (size_t)kb * A_CHUNK;
        // 144 x 16B units each for hi and lo (36 rows x 64 B)
        {
            const int u = t;          // 0..255
            if (u < 144) gload_lds16(hsrc + u * 16, &sT[buf][0][u * 16]);
            else if (u < 288) gload_lds16(hsrc + 9216 + (u - 144) * 16, &sT[buf][1][(u - 144) * 16]);
        }
        if (t < 32) {
            const int u = 112 + t;    // remaining lo units 112..143
            gload_lds16(hsrc + 9216 + u * 16, &sT[buf][1][u * 16]);
        }
    };

    i32x4 aH[3], aC[3], aL[3];
    #pragma unroll
    for (int mt = 0; mt < 3; ++mt) {
        aH[mt] = (i32x4){0,0,0,0};
        aC[mt] = (i32x4){0,0,0,0};
        aL[mt] = (i32x4){0,0,0,0};
    }

    stage(0, 0);
    __syncthreads();

    const int m18 = 18 * m;
    for (int kb = 0; kb < 8; ++kb) {
        const int buf = kb & 1;
        if (kb < 7) stage(kb + 1, buf ^ 1);
        if (wid < 3) {
            const int brow = wid * 16 + l15;
            const int bblk = kq ^ ((m18 + (brow >> 1)) & 3);
            const i32x4 bh = *(const i32x4*)&sT[buf][0][brow * 64 + bblk * 16];
            const i32x4 bl = *(const i32x4*)&sT[buf][1][brow * 64 + bblk * 16];
            #pragma unroll
            for (int mt = 0; mt < 3; ++mt) {
                const int arow = mt * 16 + l15;
                const int ablk = kq ^ ((m18 + (arow >> 1)) & 3);
                const i32x4 ah = *(const i32x4*)&sT[buf][0][arow * 64 + ablk * 16];
                const i32x4 al = *(const i32x4*)&sT[buf][1][arow * 64 + ablk * 16];
                aH[mt] = __builtin_amdgcn_mfma_i32_16x16x64_i8(ah, bh, aH[mt], 0, 0, 0);
                aC[mt] = __builtin_amdgcn_mfma_i32_16x16x64_i8(ah, bl, aC[mt], 0, 0, 0);
                aC[mt] = __builtin_amdgcn_mfma_i32_16x16x64_i8(al, bh, aC[mt], 0, 0, 0);
                aL[mt] = __builtin_amdgcn_mfma_i32_16x16x64_i8(al, bl, aL[mt], 0, 0, 0);
            }
        }
        __syncthreads();
    }

    if (wid < 3) {
        const int col = wid * 16 + l15;
        if (col < 36) {
            #pragma unroll
            for (int mt = 0; mt < 3; ++mt) {
                #pragma unroll
                for (int e = 0; e < 4; ++e) {
                    const int row = mt * 16 + kq * 4 + e;
                    if (row < 36) {
                        const float g = (float)aH[mt][e] * (1.f / 256.f)
                                      + (float)aC[mt][e] * (1.f / 65536.f)
                                      + (float)aL[mt][e] * (1.f / 16777216.f);
                        G[(size_t)i * 1296 + row * 36 + col] = g;
                    }
                }
            }
        }
    }
}

// ---------------------------------------------------------------------------
// Kernel B: block = 4 images (144 packed M-rows) x 4 caps (128 N-cols).
// 4 waves, wave = 144x32 (mt=9, nt=2). i8 EXACT split MFMA (16x16x64).
// lt (l*l) MFMAs issued FIRST per mt so the dependent VALU fold has 6
// intervening MFMAs (~120cyc) of latency cover; fold is shift-add only.
// s_setprio(1) around the MFMA cluster (2 independent blocks/CU).
// ---------------------------------------------------------------------------
__global__ __launch_bounds__(256, 2) void vsc_mfma_kernel(const u8* __restrict__ imgsT,
                                const u8* __restrict__ capsT,
                                const int* __restrict__ img_lens,
                                const int* __restrict__ cap_lens,
                                const float* __restrict__ G,
                                float* __restrict__ out) {
    extern __shared__ __align__(16) char smem[];
    const int bid = blockIdx.x;
    const int xcd = bid & 7;
    const int r_  = bid >> 3;
    const int g   = (r_ >> 5) * 8 + xcd;   // image tile 0..31 (4 imgs)
    const int cg  = r_ & 31;               // cap group 0..31 (4 caps = 128 rows)
    const int t = threadIdx.x;
    const int wid = t >> 6;                // 0..3
    const int lane = t & 63;
    const int l15 = lane & 15;
    const int kblk = lane >> 4;            // also the epilogue quad index

    const u8* gA = imgsT + (size_t)g * 8 * A_CHUNK;
    const u8* gB = capsT + (size_t)cg * 8 * B_CHUNK;

    auto stage = [&](int kb, char* buf) {
        if (wid < 2) {           // A (imgs): 18432 B, 2 waves x 9 KB
            const u8* src = gA + (size_t)kb * A_CHUNK + wid * 9216 + lane * 16;
            char* dst = buf + wid * 9216;
            #pragma unroll
            for (int jj = 0; jj < 9; ++jj)
                gload_lds16(src + jj * 1024, dst + jj * 1024);
        } else {                 // B (caps): 16384 B, 2 waves x 8 KB
            const int wb = wid - 2;
            const u8* src = gB + (size_t)kb * B_CHUNK + wb * 8192 + lane * 16;
            char* dst = buf + 18432 + wb * 8192;
            #pragma unroll
            for (int jj = 0; jj < 8; ++jj)
                gload_lds16(src + jj * 1024, dst + jj * 1024);
        }
    };

    i32x4 accH[9][2], accC[9][2];
    #pragma unroll
    for (int mt = 0; mt < 9; ++mt)
        #pragma unroll
        for (int nt = 0; nt < 2; ++nt) {
            accH[mt][nt] = (i32x4){0, 0, 0, 0};
            accC[mt][nt] = (i32x4){0, 0, 0, 0};
        }

    stage(0, smem);
    __syncthreads();

    const int blk16 = (kblk ^ ((l15 >> 1) & 3)) << 4;
    const int baseA = l15 * 64 + blk16;                // + mt*1024 ; h: +0, l: +9216
    const int baseB = (wid * 32 + l15) * 64 + blk16;   // + nt*1024 ; h: +18432, l: +26624

    for (int kb = 0; kb < 8; ++kb) {
        char* cur = smem + (size_t)(kb & 1) * BUF_BYTES;
        if (kb < 7) stage(kb + 1, smem + (size_t)((kb + 1) & 1) * BUF_BYTES);

        const i32x4 bh0 = *(const i32x4*)(cur + 18432 + baseB);
        const i32x4 bl0 = *(const i32x4*)(cur + 26624 + baseB);
        const i32x4 bh1 = *(const i32x4*)(cur + 18432 + baseB + 1024);
        const i32x4 bl1 = *(const i32x4*)(cur + 26624 + baseB + 1024);
        __builtin_amdgcn_s_setprio(1);
        #pragma unroll
        for (int mt = 0; mt < 9; ++mt) {
            const i32x4 ah = *(const i32x4*)(cur + baseA + mt * 1024);
            const i32x4 al = *(const i32x4*)(cur + 9216 + baseA + mt * 1024);
            i32x4 lt0 = (i32x4){0, 0, 0, 0};
            i32x4 lt1 = (i32x4){0, 0, 0, 0};
            lt0 = __builtin_amdgcn_mfma_i32_16x16x64_i8(al, bl0, lt0, 0, 0, 0);
            lt1 = __builtin_amdgcn_mfma_i32_16x16x64_i8(al, bl1, lt1, 0, 0, 0);
            accH[mt][0] = __builtin_amdgcn_mfma_i32_16x16x64_i8(ah, bh0, accH[mt][0], 0, 0, 0);
            accH[mt][1] = __builtin_amdgcn_mfma_i32_16x16x64_i8(ah, bh1, accH[mt][1], 0, 0, 0);
            accC[mt][0] = __builtin_amdgcn_mfma_i32_16x16x64_i8(ah, bl0, accC[mt][0], 0, 0, 0);
            accC[mt][0] = __builtin_amdgcn_mfma_i32_16x16x64_i8(al, bh0, accC[mt][0], 0, 0, 0);
            accC[mt][1] = __builtin_amdgcn_mfma_i32_16x16x64_i8(ah, bl1, accC[mt][1], 0, 0, 0);
            accC[mt][1] = __builtin_amdgcn_mfma_i32_16x16x64_i8(al, bh1, accC[mt][1], 0, 0, 0);
            #pragma unroll
            for (int e = 0; e < 4; ++e) {
                accC[mt][0][e] += lt0[e] >> 8;   // truncation bias <= 1.2e-3 s-units
                accC[mt][1][e] += lt1[e] >> 8;
            }
        }
        __builtin_amdgcn_s_setprio(0);
        __syncthreads();
    }

    // ---- stage Gram (4 imgs, fp32) into retired staging LDS
    float* sG = (float*)smem;
    {
        const float4* src = (const float4*)(G + (size_t)g * 4 * 1296);
        for (int idx = t; idx < 1296; idx += 256)
            ((float4*)sG)[idx] = src[idx];
    }
    __syncthreads();

    int ilen_[4];
    #pragma unroll
    for (int j = 0; j < 4; ++j) ilen_[j] = img_lens[g * 4 + j];

    #pragma unroll
    for (int nt = 0; nt < 2; ++nt) {
        const int col = wid * 32 + nt * 16 + l15;     // 0..127 cap-word col
        const int c = cg * 4 + (col >> 5);
        const int w = col & 31;
        const int clen = cap_lens[c];
        #pragma unroll
        for (int j = 0; j < 4; ++j) {
            const int mtb = (36 * j) >> 4;            // 0,2,4,6
            const int ilenj = ilen_[j];
            // branchless local top-5 over this lane's rows of img j (rr in bits 0..5)
            float tv0 = NEGV, tv1 = NEGV, tv2 = NEGV, tv3 = NEGV, tv4 = NEGV;
            #pragma unroll
            for (int dm = 0; dm < 3; ++dm) {
                #pragma unroll
                for (int e = 0; e < 4; ++e) {
                    const int mt = mtb + dm;
                    const int r = mt * 16 + kblk * 4 + e;
                    const int rr = r - 36 * j;
                    // inline fold: S = 10*(HH/256 + CR/65536) (CR includes LL>>8)
                    const float sval = (float)accH[mt][nt][e] * (10.f / 256.f)
                                     + (float)accC[mt][nt][e] * (10.f / 65536.f);
                    float v = NEGV;
                    if ((unsigned)rr < (unsigned)ilenj)
                        v = __uint_as_float((__float_as_uint(sval) & ~63u) | (u32)rr);
                    const bool c0 = v > tv0, c1 = v > tv1, c2 = v > tv2, c3 = v > tv3, c4 = v > tv4;
                    const float n4 = c4 ? (c3 ? tv3 : v) : tv4;
                    const float n3 = c3 ? (c2 ? tv2 : v) : tv3;
                    const float n2 = c2 ? (c1 ? tv1 : v) : tv2;
                    const float n1 = c1 ? (c0 ? tv0 : v) : tv1;
                    const float n0 = c0 ? v : tv0;
                    tv0 = n0; tv1 = n1; tv2 = n2; tv3 = n3; tv4 = n4;
                }
            }
            // 2-step butterfly sorted-merge across the 4-lane quad (lane^16, lane^32)
            float ta[5] = {tv0, tv1, tv2, tv3, tv4};
            #pragma unroll
            for (int st = 0; st < 2; ++st) {
                const int dx = 16 << st;
                float tb[5];
                #pragma unroll
                for (int s = 0; s < 5; ++s) tb[s] = __shfl_xor(ta[s], dx);
                float na[5];
                #pragma unroll
                for (int k = 0; k < 5; ++k) {
                    float best = fmaxf(ta[k], tb[k]);
                    #pragma unroll
                    for (int i2 = 1; i2 <= k; ++i2)
                        best = fmaxf(best, fminf(ta[i2 - 1], tb[k - i2]));
                    na[k] = best;
                }
                #pragma unroll
                for (int s = 0; s < 5; ++s) ta[s] = na[s];
            }
            // softmax over the 5
            const float m = ta[0];
            const float p0 = 1.f;
            const float p1 = expf(ta[1] - m);
            const float p2 = expf(ta[2] - m);
            const float p3 = expf(ta[3] - m);
            const float p4 = expf(ta[4] - m);
            const float sum = p0 + p1 + p2 + p3 + p4;
            const float num = p0 * ta[0] + p1 * ta[1] + p2 * ta[2] + p3 * ta[3] + p4 * ta[4];
            const int r0 = __float_as_uint(ta[0]) & 63;
            const int r1 = __float_as_uint(ta[1]) & 63;
            const int r2 = __float_as_uint(ta[2]) & 63;
            const int r3 = __float_as_uint(ta[3]) & 63;
            const int r4 = __float_as_uint(ta[4]) & 63;
            const float* gj = sG + j * 1296;
            // den2 = sum_{a,b} p_a p_b G[ra][rb]; a-rows split across the quad
            const float pa = (kblk == 0) ? p0 : (kblk == 1) ? p1 : (kblk == 2) ? p2 : p3;
            const int   ra = (kblk == 0) ? r0 : (kblk == 1) ? r1 : (kblk == 2) ? r2 : r3;
            const float* grow = gj + ra * 36;
            float part = pa * (p0 * grow[r0] + p1 * grow[r1] + p2 * grow[r2]
                             + p3 * grow[r3] + p4 * grow[r4]);
            if (kblk == 0) {
                const float* grow4 = gj + r4 * 36;
                part += p4 * (p0 * grow4[r0] + p1 * grow4[r1] + p2 * grow4[r2]
                            + p3 * grow4[r3] + p4 * grow4[r4]);
            }
            part += __shfl_xor(part, 16);
            part += __shfl_xor(part, 32);
            if (kblk == j) {
                float result = -1.f;
                if (w < clen) {
                    const float inv = 1.f / sum;
                    const float a_ = 0.1f * num * inv;
                    const float den = sqrtf(part) * inv + (-1e-8f);
                    result = a_ / den;
                }
                out[((size_t)(g * 4 + j) * N_CAP + c) * MAX_W + w] = result;
            }
        }
    }
}

extern "C" void kernel_launch(void* const* d_in, const int* in_sizes, int n_in,
                              void* d_out, int out_size, void* d_ws, size_t ws_size,
                              hipStream_t stream) {
    const float* imgs     = (const float*)d_in[0];
    const float* caps     = (const float*)d_in[1];
    const int*   img_lens = (const int*)d_in[2];
    const int*   cap_lens = (const int*)d_in[3];
    float* out = (float*)d_out;

    // d_ws layout
    float* G  = (float*)d_ws;                          // 128*1296*4 = 663552 B
    u8* imgsT = (u8*)d_ws + 663552;                    // 32*8*18432 = 4718592 B
    u8* capsT = imgsT + (size_t)32 * 8 * A_CHUNK;      // 32*8*16384 = 4194304 B

    hipFuncSetAttribute((const void*)vsc_mfma_kernel,
                        hipFuncAttributeMaxDynamicSharedMemorySize, LDS_BYTES);

    convert_kernel<<<2048, 256, 0, stream>>>(imgs, caps, imgsT, capsT);
    gram_i8_kernel<<<N_IMG, 256, 0, stream>>>(imgsT, G);
    vsc_mfma_kernel<<<1024, 256, LDS_BYTES, stream>>>(imgsT, capsT, img_lens, cap_lens, G, out);
}